// Round 4
// baseline (647.888 us; speedup 1.0000x reference)
//
#include <hip/hip_runtime.h>
#include <stdint.h>

typedef __attribute__((ext_vector_type(8))) short short8;
typedef __attribute__((ext_vector_type(4))) float f32x4;

#define NN 1024
#define NBATCH 16384

__device__ __forceinline__ unsigned short f32_to_bf16_rne(float f) {
  unsigned int u = __float_as_uint(f);
  unsigned int r = (u + 0x7fffu + ((u >> 16) & 1u)) >> 16;
  return (unsigned short)r;
}

__device__ __forceinline__ unsigned int pack2bf(float lo, float hi) {
  return (unsigned int)f32_to_bf16_rne(lo) | ((unsigned int)f32_to_bf16_rne(hi) << 16);
}

// 64-lane all-reduce sum: 4 DPP (VALU) stages + ds_swizzle xor16 + shfl xor32.
__device__ __forceinline__ float allsum64(float x) {
  x += __int_as_float(__builtin_amdgcn_update_dpp(0, __float_as_int(x), 0xB1, 0xF, 0xF, true));   // xor1
  x += __int_as_float(__builtin_amdgcn_update_dpp(0, __float_as_int(x), 0x4E, 0xF, 0xF, true));   // xor2
  x += __int_as_float(__builtin_amdgcn_update_dpp(0, __float_as_int(x), 0x141, 0xF, 0xF, true));  // xor4 (row_half_mirror)
  x += __int_as_float(__builtin_amdgcn_update_dpp(0, __float_as_int(x), 0x140, 0xF, 0xF, true));  // xor8 (row_mirror)
  x += __int_as_float(__builtin_amdgcn_ds_swizzle(__float_as_int(x), 0x401F));                    // xor16
  x += __shfl_xor(x, 32);
  return x;
}

// -------------------- prep: tau = 2/(u.u), sigmas --------------------
__global__ __launch_bounds__(256) void prep_kernel(
    const float* __restrict__ U, const float* __restrict__ V,
    const float* __restrict__ p, float* __restrict__ tau_u,
    float* __restrict__ tau_v, float* __restrict__ sigmas) {
  int wave = threadIdx.x >> 6, lane = threadIdx.x & 63;
  int row = blockIdx.x * 4 + wave;
  if (row < 2048) {
    const float* u = (row < NN) ? (U + (size_t)row * NN) : (V + (size_t)(row - NN) * NN);
    float s = 0.f;
#pragma unroll
    for (int t = 0; t < 16; ++t) { float a = u[lane + (t << 6)]; s += a * a; }
    s = allsum64(s);
    if (lane == 0) {
      float tau = 2.0f / s;
      if (row < NN) tau_u[row] = tau;
      else tau_v[row - NN] = tau;
    }
  } else if (row < 2064) {
    int j = ((row - 2048) << 6) + lane;
    float pj = p[j];
    float sg = 1.0f / (1.0f + expf(-pj));
    sigmas[j] = 0.9f * (sg - 0.5f) + 0.55f;  // r=0.45, mean=0.55
  }
}

// -------------------- gram + T8 per block of 8 reflectors --------------------
// blk<128: U bank, rows 8*blk+j (j=0..7). blk>=128: s=blk-128, V bank, rows 1023-8s-j.
__global__ __launch_bounds__(64) void gram_t8_kernel(
    const float* __restrict__ U, const float* __restrict__ V,
    const float* __restrict__ tau_u, const float* __restrict__ tau_v,
    float* __restrict__ T8all) {
  __shared__ float G[64];
  const int blk = blockIdx.x;
  const int lane = threadIdx.x;
  const float* bank;
  int rbase, rsign, st;
  if (blk < 128) { bank = U; rbase = 8 * blk; rsign = 1; st = 8 * blk; }
  else { int s = blk - 128; bank = V; rbase = 1023 - 8 * s; rsign = -1; st = 1016 - 8 * s; }

  if (lane < 28) {
    int j = 1, k = 0, t = lane;
    for (int jj = 1; jj < 8; ++jj) {
      int lo = jj * (jj - 1) / 2, hi = jj * (jj + 1) / 2;
      if (t >= lo && t < hi) { j = jj; k = t - lo; }
    }
    const float* rk = bank + (size_t)(rbase + rsign * k) * NN;
    const float* rj = bank + (size_t)(rbase + rsign * j) * NN;
    float acc = 0.f;
    for (int i = st >> 2; i < 256; ++i) {
      float4 a = *reinterpret_cast<const float4*>(rk + 4 * i);
      float4 b = *reinterpret_cast<const float4*>(rj + 4 * i);
      acc += a.x * b.x + a.y * b.y + a.z * b.z + a.w * b.w;
    }
    G[k * 8 + j] = acc;
  }
  __syncthreads();

  if (lane < 8) {
    float Tr[8];
#pragma unroll
    for (int j = 0; j < 8; ++j) Tr[j] = 0.f;
#pragma unroll
    for (int j = 0; j < 8; ++j) {
      int grow = rbase + rsign * j;
      float tj = (blk < 128) ? tau_u[grow] : tau_v[grow];
      float a = 0.f;
#pragma unroll
      for (int k = 0; k < 8; ++k) {
        if (k < j) a += Tr[k] * G[k * 8 + j];
      }
      Tr[j] = (lane == j) ? tj : (-tj * a);
    }
#pragma unroll
    for (int j = 0; j < 8; ++j) T8all[(size_t)blk * 64 + lane * 8 + j] = Tr[j];
  }
}

// -------------------- build 4 half-chains: 512 blocks x 512 threads --------------------
// chain 0: Alo = H_u0..H_u511      (asc,  q0 segs {0,1}),  store row-major
// chain 1: Ahi = H_u512..H_u1023   (asc,  q0 segs {2,3}),  store transposed
// chain 2: Bhi = H_v1023..H_v512   (desc, q0 segs {3,2}),  store row-major
// chain 3: Blo = H_v511..H_v0      (desc, q0 segs {1,0}),  store transposed
// Element map: v[4q+r] holds e = 256q + 4*lane + r. Wave w owns row (bid&127)*8+w
// and stages reflector slot w's 4 quarters.
__device__ __forceinline__ void stage4(int chain, int step, float* lbuf, float* tbuf,
    const float* __restrict__ U, const float* __restrict__ V,
    const float* __restrict__ T8all, int wave, int lane) {
  if (step >= 64) return;
  int q0, rbase, rsign, t8i;
  const float* bank;
  switch (chain) {
    case 0:  q0 = step >> 5;              bank = U; rbase = 8 * step;        rsign = 1;  t8i = step;       break;
    case 1:  q0 = 2 + (step >> 5);        bank = U; rbase = 512 + 8 * step;  rsign = 1;  t8i = 64 + step;  break;
    case 2:  q0 = (1016 - 8 * step) >> 8; bank = V; rbase = 1023 - 8 * step; rsign = -1; t8i = 128 + step; break;
    default: q0 = (504 - 8 * step) >> 8;  bank = V; rbase = 511 - 8 * step;  rsign = -1; t8i = 192 + step; break;
  }
  const int grow = rbase + rsign * wave;
  const float* gbase = bank + (size_t)grow * NN;
  float* lrow = lbuf + wave * NN;
#pragma unroll
  for (int q = 0; q < 4; ++q) {
    if (q < q0) continue;
    __builtin_amdgcn_global_load_lds(
        (const __attribute__((address_space(1))) void*)(gbase + q * 256 + lane * 4),
        (__attribute__((address_space(3))) void*)(lrow + q * 256), 16, 0, 0);
  }
  if (wave == 0 && lane < 16) {
    float4 t = *reinterpret_cast<const float4*>(T8all + (size_t)t8i * 64 + lane * 4);
    *reinterpret_cast<float4*>(tbuf + lane * 4) = t;
  }
}

template <int Q0>
__device__ __forceinline__ void apply_block(const float* __restrict__ ub,
    const float* __restrict__ tb, float* __restrict__ v, int lane) {
  float uc[8][(4 - Q0) * 4];
  float c[8];
#pragma unroll
  for (int j = 0; j < 8; ++j) {
    float acc = 0.f;
#pragma unroll
    for (int q = Q0; q < 4; ++q) {
      const float4 uu = *reinterpret_cast<const float4*>(&ub[j * NN + q * 256 + lane * 4]);
      const int ci = (q - Q0) * 4;
      uc[j][ci + 0] = uu.x; uc[j][ci + 1] = uu.y;
      uc[j][ci + 2] = uu.z; uc[j][ci + 3] = uu.w;
      acc += uu.x * v[4 * q + 0] + uu.y * v[4 * q + 1] +
             uu.z * v[4 * q + 2] + uu.w * v[4 * q + 3];
    }
    c[j] = acc;
  }
#pragma unroll
  for (int j = 0; j < 8; ++j) c[j] = allsum64(c[j]);
  float w[8];
#pragma unroll
  for (int j = 0; j < 8; ++j) {
    float acc = 0.f;
#pragma unroll
    for (int k = 0; k < 8; ++k) {
      if (k <= j) acc += c[k] * tb[k * 8 + j];
    }
    w[j] = acc;
  }
#pragma unroll
  for (int q = Q0; q < 4; ++q) {
#pragma unroll
    for (int r = 0; r < 4; ++r) {
      float acc = v[4 * q + r];
#pragma unroll
      for (int j = 0; j < 8; ++j) acc -= w[j] * uc[j][(q - Q0) * 4 + r];
      v[4 * q + r] = acc;
    }
  }
}

__global__ __launch_bounds__(512, 4) void build4_kernel(
    const float* __restrict__ U, const float* __restrict__ V,
    const float* __restrict__ T8all,
    unsigned short* __restrict__ Alo, unsigned short* __restrict__ S1,
    unsigned short* __restrict__ Bhi, unsigned short* __restrict__ S3) {
  __shared__ float ubuf[2][8 * NN];
  __shared__ float tbuf[2][64];
  const int tid = threadIdx.x;
  const int wave = tid >> 6, lane = tid & 63;
  const int chain = blockIdx.x >> 7;
  const int row = ((blockIdx.x & 127) << 3) + wave;

  float v[16];
#pragma unroll
  for (int q = 0; q < 4; ++q)
#pragma unroll
    for (int r = 0; r < 4; ++r)
      v[4 * q + r] = (256 * q + 4 * lane + r == row) ? 1.0f : 0.0f;

  stage4(chain, 0, ubuf[0], tbuf[0], U, V, T8all, wave, lane);
  int pb = 0;

#define SEG(Q0C, BASE)                                                            \
  for (int s = 0; s < 32; ++s) {                                                  \
    const int step = (BASE) + s;                                                  \
    __syncthreads(); /* vmcnt drained: staged buf ready, prev buf consumed */     \
    stage4(chain, step + 1, ubuf[pb ^ 1], tbuf[pb ^ 1], U, V, T8all, wave, lane); \
    apply_block<Q0C>(ubuf[pb], tbuf[pb], v, lane);                                \
    pb ^= 1;                                                                      \
  }

  if (chain == 0)      { SEG(0, 0) SEG(1, 32) }
  else if (chain == 1) { SEG(2, 0) SEG(3, 32) }
  else if (chain == 2) { SEG(3, 0) SEG(2, 32) }
  else                 { SEG(1, 0) SEG(0, 32) }
#undef SEG

  if (chain == 0 || chain == 2) {
    unsigned short* dst = (chain == 0) ? Alo : Bhi;
#pragma unroll
    for (int q = 0; q < 4; ++q) {
      ushort4 pk;
      pk.x = f32_to_bf16_rne(v[4 * q + 0]);
      pk.y = f32_to_bf16_rne(v[4 * q + 1]);
      pk.z = f32_to_bf16_rne(v[4 * q + 2]);
      pk.w = f32_to_bf16_rne(v[4 * q + 3]);
      *reinterpret_cast<ushort4*>(&dst[(size_t)row * NN + 256 * q + 4 * lane]) = pk;
    }
  } else {
    unsigned short* dst = (chain == 1) ? S1 : S3;
#pragma unroll
    for (int q = 0; q < 4; ++q)
#pragma unroll
      for (int r = 0; r < 4; ++r)
        dst[(size_t)(256 * q + 4 * lane + r) * NN + row] = f32_to_bf16_rne(v[4 * q + r]);
  }
}

// -------------------- generic 1024^3 bf16 compose: D[m][n] = sum_k X[m][k]*W[n][k] --------------------
#define BM 128
#define BN 128
#define BK 32
#define LDK 40

__device__ __forceinline__ void compose_body(
    const unsigned short* __restrict__ Xb, const unsigned short* __restrict__ Wb,
    unsigned short* __restrict__ Op, const float* __restrict__ sig, int b) {
  __shared__ unsigned short As[BM * LDK];
  __shared__ unsigned short Bs[BN * LDK];
  const int tid = threadIdx.x;
  const int lane = tid & 63, wave = tid >> 6;
  const int bm = b & 7, bn = b >> 3;
  const int m0 = bm * BM, n0 = bn * BN;
  const int wm = wave & 1, wn = wave >> 1;

  const int srow = tid >> 1;
  const int scol = (tid & 1) << 4;
  const unsigned short* aptr = Xb + (size_t)(m0 + srow) * NN + scol;
  const unsigned short* bptr = Wb + (size_t)(n0 + srow) * NN + scol;

  f32x4 acc[4][4];
#pragma unroll
  for (int a = 0; a < 4; ++a)
#pragma unroll
    for (int bb = 0; bb < 4; ++bb) acc[a][bb] = 0.f;

  uint4 ra0 = *reinterpret_cast<const uint4*>(aptr + 0);
  uint4 ra1 = *reinterpret_cast<const uint4*>(aptr + 8);
  uint4 rb0 = *reinterpret_cast<const uint4*>(bptr + 0);
  uint4 rb1 = *reinterpret_cast<const uint4*>(bptr + 8);

  const int arow0 = wm * 64;
  const int brow0 = wn * 64;
  const int fr = lane & 15;
  const int kb = (lane >> 4) << 3;

#pragma unroll 1
  for (int kt = 0; kt < NN / BK; ++kt) {
    __syncthreads();
    *reinterpret_cast<uint4*>(&As[srow * LDK + scol]) = ra0;
    *reinterpret_cast<uint4*>(&As[srow * LDK + scol + 8]) = ra1;
    *reinterpret_cast<uint4*>(&Bs[srow * LDK + scol]) = rb0;
    *reinterpret_cast<uint4*>(&Bs[srow * LDK + scol + 8]) = rb1;
    __syncthreads();
    if (kt + 1 < NN / BK) {
      const unsigned short* ap = aptr + (kt + 1) * BK;
      const unsigned short* bp = bptr + (kt + 1) * BK;
      ra0 = *reinterpret_cast<const uint4*>(ap + 0);
      ra1 = *reinterpret_cast<const uint4*>(ap + 8);
      rb0 = *reinterpret_cast<const uint4*>(bp + 0);
      rb1 = *reinterpret_cast<const uint4*>(bp + 8);
    }
    short8 af[4], bf[4];
#pragma unroll
    for (int tr = 0; tr < 4; ++tr)
      af[tr] = *reinterpret_cast<const short8*>(&As[(arow0 + tr * 16 + fr) * LDK + kb]);
#pragma unroll
    for (int tc = 0; tc < 4; ++tc)
      bf[tc] = *reinterpret_cast<const short8*>(&Bs[(brow0 + tc * 16 + fr) * LDK + kb]);
#pragma unroll
    for (int tr = 0; tr < 4; ++tr)
#pragma unroll
      for (int tc = 0; tc < 4; ++tc)
        acc[tr][tc] = __builtin_amdgcn_mfma_f32_16x16x32_bf16(af[tr], bf[tc], acc[tr][tc], 0, 0, 0);
  }

  const int rq = (lane >> 4) << 2;
#pragma unroll
  for (int tc = 0; tc < 4; ++tc) {
    const int gc = n0 + brow0 + tc * 16 + fr;
    const float s = sig ? sig[gc] : 1.0f;
#pragma unroll
    for (int tr = 0; tr < 4; ++tr) {
      const int gr = m0 + arow0 + tr * 16 + rq;
#pragma unroll
      for (int q = 0; q < 4; ++q) {
        Op[(size_t)(gr + q) * NN + gc] = f32_to_bf16_rne(acc[tr][tc][q] * s);
      }
    }
  }
}

// #1 and #2 fused (independent): 128 blocks.
__global__ __launch_bounds__(256) void composeAB_kernel(
    const unsigned short* __restrict__ Alo, const unsigned short* __restrict__ S1,
    const unsigned short* __restrict__ Bhi, const unsigned short* __restrict__ S3,
    const float* __restrict__ sigmas,
    unsigned short* __restrict__ Asig, unsigned short* __restrict__ Bt2) {
  const int b = blockIdx.x;
  if (b < 64) {
    // Asig[k][j] = (sum_m Alo[k][m] * Ahi[m][j]) * sigma_j ; S1[j][m] = Ahi[m][j]
    compose_body(Alo, S1, Asig, sigmas, b);
  } else {
    // Bt2[n][j] = sum_m Blo[m][n] * Bhi[j][m] = B[j][n] ; S3[n][m] = Blo[m][n]
    compose_body(S3, Bhi, Bt2, nullptr, b - 64);
  }
}

// #3: Mt[n][k] = sum_j Bt2[n][j] * Asig[k][j]. 64 blocks.
__global__ __launch_bounds__(256) void composeMt_kernel(
    const unsigned short* __restrict__ Bt2, const unsigned short* __restrict__ Asig,
    unsigned short* __restrict__ Mt) {
  compose_body(Bt2, Asig, Mt, nullptr, blockIdx.x);
}

// -------------------- GEMM: out = x @ M + bias (X f32 -> bf16 on the fly) ----
__global__ __launch_bounds__(256) void gemm_kernel(
    const float* __restrict__ X, const unsigned short* __restrict__ Mt,
    const float* __restrict__ bias, float* __restrict__ Out) {
  __shared__ unsigned short As[BM * LDK];
  __shared__ unsigned short Bs[BN * LDK];
  const int tid = threadIdx.x;
  const int lane = tid & 63, wave = tid >> 6;
  const int bm = blockIdx.x & 127;
  const int bn = blockIdx.x >> 7;
  const int m0 = bm * BM, n0 = bn * BN;
  const int wm = wave & 1, wn = wave >> 1;

  const int srow = tid >> 1;
  const int scol = (tid & 1) << 4;
  const float* aptr = X + (size_t)(m0 + srow) * NN + scol;
  const unsigned short* bptr = Mt + (size_t)(n0 + srow) * NN + scol;

  f32x4 acc[4][4];
#pragma unroll
  for (int a = 0; a < 4; ++a)
#pragma unroll
    for (int b = 0; b < 4; ++b) acc[a][b] = 0.f;

  float4 ra0 = *reinterpret_cast<const float4*>(aptr + 0);
  float4 ra1 = *reinterpret_cast<const float4*>(aptr + 4);
  float4 ra2 = *reinterpret_cast<const float4*>(aptr + 8);
  float4 ra3 = *reinterpret_cast<const float4*>(aptr + 12);
  uint4 rb0 = *reinterpret_cast<const uint4*>(bptr + 0);
  uint4 rb1 = *reinterpret_cast<const uint4*>(bptr + 8);

  const int arow0 = wm * 64;
  const int brow0 = wn * 64;
  const int fr = lane & 15;
  const int kb = (lane >> 4) << 3;

#pragma unroll 1
  for (int kt = 0; kt < NN / BK; ++kt) {
    __syncthreads();
    uint4 w0, w1;
    w0.x = pack2bf(ra0.x, ra0.y); w0.y = pack2bf(ra0.z, ra0.w);
    w0.z = pack2bf(ra1.x, ra1.y); w0.w = pack2bf(ra1.z, ra1.w);
    w1.x = pack2bf(ra2.x, ra2.y); w1.y = pack2bf(ra2.z, ra2.w);
    w1.z = pack2bf(ra3.x, ra3.y); w1.w = pack2bf(ra3.z, ra3.w);
    *reinterpret_cast<uint4*>(&As[srow * LDK + scol]) = w0;
    *reinterpret_cast<uint4*>(&As[srow * LDK + scol + 8]) = w1;
    *reinterpret_cast<uint4*>(&Bs[srow * LDK + scol]) = rb0;
    *reinterpret_cast<uint4*>(&Bs[srow * LDK + scol + 8]) = rb1;
    __syncthreads();
    if (kt + 1 < NN / BK) {
      const float* ap = aptr + (kt + 1) * BK;
      const unsigned short* bp = bptr + (kt + 1) * BK;
      ra0 = *reinterpret_cast<const float4*>(ap + 0);
      ra1 = *reinterpret_cast<const float4*>(ap + 4);
      ra2 = *reinterpret_cast<const float4*>(ap + 8);
      ra3 = *reinterpret_cast<const float4*>(ap + 12);
      rb0 = *reinterpret_cast<const uint4*>(bp + 0);
      rb1 = *reinterpret_cast<const uint4*>(bp + 8);
    }
    short8 af[4], bf[4];
#pragma unroll
    for (int tr = 0; tr < 4; ++tr)
      af[tr] = *reinterpret_cast<const short8*>(&As[(arow0 + tr * 16 + fr) * LDK + kb]);
#pragma unroll
    for (int tc = 0; tc < 4; ++tc)
      bf[tc] = *reinterpret_cast<const short8*>(&Bs[(brow0 + tc * 16 + fr) * LDK + kb]);
#pragma unroll
    for (int tr = 0; tr < 4; ++tr)
#pragma unroll
      for (int tc = 0; tc < 4; ++tc)
        acc[tr][tc] = __builtin_amdgcn_mfma_f32_16x16x32_bf16(af[tr], bf[tc], acc[tr][tc], 0, 0, 0);
  }

  const int rq = (lane >> 4) << 2;
#pragma unroll
  for (int tc = 0; tc < 4; ++tc) {
    const int gc = n0 + brow0 + tc * 16 + fr;
    const float bv = bias[gc];
#pragma unroll
    for (int tr = 0; tr < 4; ++tr) {
      const int gr = m0 + arow0 + tr * 16 + rq;
#pragma unroll
      for (int q = 0; q < 4; ++q) {
        Out[(size_t)(gr + q) * NN + gc] = acc[tr][tc][q] + bv;
      }
    }
  }
}

extern "C" void kernel_launch(void* const* d_in, const int* in_sizes, int n_in,
                              void* d_out, int out_size, void* d_ws, size_t ws_size,
                              hipStream_t stream) {
  const float* x = (const float*)d_in[0];
  const float* U = (const float*)d_in[1];
  const float* V = (const float*)d_in[2];
  const float* p = (const float*)d_in[3];
  const float* bias = (const float*)d_in[4];
  float* out = (float*)d_out;

  char* ws = (char*)d_ws;
  float* tau_u = (float*)(ws);
  float* tau_v = (float*)(ws + 4096);
  float* sigmas = (float*)(ws + 8192);
  float* T8all = (float*)(ws + 16384);                 // 64 KB
  unsigned short* Mt = (unsigned short*)(ws + 81920);  // 2 MB (must survive until gemm)

  // Large temporaries live in d_out (64 MB) and are fully consumed before gemm
  // overwrites d_out. 6 matrices x 1M bf16 elements = 12 MB.
  unsigned short* sc = (unsigned short*)d_out;
  const size_t ME = (size_t)NN * NN;
  unsigned short* Alo  = sc + 0 * ME;  // row-major  Alo[k][m]
  unsigned short* S1   = sc + 1 * ME;  // transposed S1[j][m] = Ahi[m][j]
  unsigned short* Bhi  = sc + 2 * ME;  // row-major  Bhi[j][m]
  unsigned short* S3   = sc + 3 * ME;  // transposed S3[n][m] = Blo[m][n]
  unsigned short* Asig = sc + 4 * ME;  // Asig[k][j] = A[k][j]*sigma_j
  unsigned short* Bt2  = sc + 5 * ME;  // Bt2[n][j]  = B[j][n]

  prep_kernel<<<516, 256, 0, stream>>>(U, V, p, tau_u, tau_v, sigmas);
  gram_t8_kernel<<<256, 64, 0, stream>>>(U, V, tau_u, tau_v, T8all);
  build4_kernel<<<512, 512, 0, stream>>>(U, V, T8all, Alo, S1, Bhi, S3);
  composeAB_kernel<<<128, 256, 0, stream>>>(Alo, S1, Bhi, S3, sigmas, Asig, Bt2);
  composeMt_kernel<<<64, 256, 0, stream>>>(Bt2, Asig, Mt);
  gemm_kernel<<<1024, 256, 0, stream>>>(x, Mt, bias, out);
}